// Round 3
// baseline (334.080 us; speedup 1.0000x reference)
//
#include <hip/hip_runtime.h>
#include <cstdint>
#include <cstddef>

typedef __bf16 bf16;
typedef __attribute__((ext_vector_type(8))) __bf16 bf16x8;
typedef __attribute__((ext_vector_type(4))) float f32x4;
typedef __attribute__((ext_vector_type(4))) unsigned short u16x4;
typedef __attribute__((ext_vector_type(8))) unsigned short u16x8;

#define DEV __device__ __forceinline__

// fp32 -> bf16 round-to-nearest-even (explicit, deterministic)
DEV unsigned short f2bf(float f) {
    unsigned int u = __builtin_bit_cast(unsigned int, f);
    u += 0x7FFFu + ((u >> 16) & 1u);
    return (unsigned short)(u >> 16);
}

DEV float bf2f(unsigned short h) {
    unsigned int u = ((unsigned int)h) << 16;
    return __builtin_bit_cast(float, u);
}

// async global->LDS, 16B per lane; lds base must be wave-uniform (HW adds lane*16)
DEV void gload16(const void* g, void* l) {
    __builtin_amdgcn_global_load_lds(
        (const __attribute__((address_space(1))) unsigned int*)g,
        (__attribute__((address_space(3))) unsigned int*)l, 16, 0, 0);
}

DEV f32x4 mfma16(bf16x8 a, bf16x8 b, f32x4 c) {
    return __builtin_amdgcn_mfma_f32_16x16x32_bf16(a, b, c, 0, 0, 0);
}

// ---------------------------------------------------------------------------
// K0: weight conversion. q-rows of w_qkv get softmax scale (1/16) * log2(e)
// folded in, so attention logits are already in log2 domain.
// ---------------------------------------------------------------------------
__global__ void k_wconv(const float* __restrict__ wqkv, const float* __restrict__ wproj,
                        unsigned short* __restrict__ wq, unsigned short* __restrict__ wp) {
    int i = blockIdx.x * 256 + threadIdx.x;   // grid covers 768*256 + 256*256 exactly
    if (i < 768 * 256) {
        float v = wqkv[i];
        if (i < 256 * 256) v *= 0.09016844005556022f;  // (1/16)*log2(e)
        wq[i] = f2bf(v);
    } else {
        int j = i - 768 * 256;
        wp[j] = f2bf(wproj[j]);
    }
}

// ---------------------------------------------------------------------------
// K1: GroupNorm stats. One block per (b, group): 8 channels * 4096 = 32768 f32.
// ---------------------------------------------------------------------------
__global__ __launch_bounds__(256) void k_gnstats(const float* __restrict__ x,
                                                 float* __restrict__ stats) {
    int bg = blockIdx.x;  // b*32 + g
    const float4* xp = (const float4*)(x + (size_t)bg * 32768);
    int t = threadIdx.x;
    float s = 0.f, sq = 0.f;
    #pragma unroll 4
    for (int i = 0; i < 32; ++i) {
        float4 v = xp[t + i * 256];
        s  += v.x + v.y + v.z + v.w;
        sq += v.x * v.x + v.y * v.y + v.z * v.z + v.w * v.w;
    }
    #pragma unroll
    for (int m = 1; m < 64; m <<= 1) { s += __shfl_xor(s, m); sq += __shfl_xor(sq, m); }
    __shared__ float red[8];
    int w = t >> 6;
    if ((t & 63) == 0) { red[w] = s; red[4 + w] = sq; }
    __syncthreads();
    if (t == 0) {
        s  = red[0] + red[1] + red[2] + red[3];
        sq = red[4] + red[5] + red[6] + red[7];
        float mean = s * (1.f / 32768.f);
        float var  = sq * (1.f / 32768.f) - mean * mean;
        stats[bg * 2]     = mean;
        stats[bg * 2 + 1] = rsqrtf(var + 1e-5f);
    }
}

// ---------------------------------------------------------------------------
// K2: apply GroupNorm -> xn fp32 (b,c,n) [residual] + xnT bf16 (b,n,c) [GEMM A]
// ---------------------------------------------------------------------------
__global__ __launch_bounds__(256) void k_gnapply(const float* __restrict__ x,
        const float* __restrict__ scale, const float* __restrict__ bias,
        const float* __restrict__ stats, float* __restrict__ xn,
        unsigned short* __restrict__ xnT) {
    __shared__ __align__(16) unsigned short tsm[64][72];
    int t = threadIdx.x;
    int nb = blockIdx.x * 64, cb = blockIdx.y * 64, b = blockIdx.z;
    int cl = t >> 2, nc = (t & 3) * 16;
    int cg = cb + cl;
    float mean = stats[(b * 32 + (cg >> 3)) * 2];
    float rstd = stats[(b * 32 + (cg >> 3)) * 2 + 1];
    float sc = scale[cg] * rstd;
    float bi = bias[cg] - mean * sc;      // xn = x*sc + bi
    const float4* xrow = (const float4*)(x  + ((size_t)(b * 256 + cg)) * 4096 + nb + nc);
    float4*      orow  = (float4*)      (xn + ((size_t)(b * 256 + cg)) * 4096 + nb + nc);
    #pragma unroll
    for (int j = 0; j < 4; ++j) {
        float4 v = xrow[j];
        v.x = v.x * sc + bi; v.y = v.y * sc + bi; v.z = v.z * sc + bi; v.w = v.w * sc + bi;
        orow[j] = v;
        u16x4 us;
        us[0] = f2bf(v.x); us[1] = f2bf(v.y); us[2] = f2bf(v.z); us[3] = f2bf(v.w);
        *(u16x4*)&tsm[cl][nc + j * 4] = us;
    }
    __syncthreads();
    int nl = t >> 2, cc = (t & 3) * 16;
    u16x8 o0, o1;
    #pragma unroll
    for (int j = 0; j < 8; ++j) { o0[j] = tsm[cc + j][nl]; o1[j] = tsm[cc + 8 + j][nl]; }
    unsigned short* dst = xnT + ((size_t)(b * 4096 + nb + nl)) * 256 + cb + cc;
    *(u16x8*)dst = o0;
    *(u16x8*)(dst + 8) = o1;
}

// ---------------------------------------------------------------------------
// K3: QKV GEMM. qkvT(16384, 768) = xnT(16384,256) @ w_qkv^T.  64x64 tile, K=256.
// ---------------------------------------------------------------------------
__global__ __launch_bounds__(256) void k_qkv(const unsigned short* __restrict__ xnT,
        const unsigned short* __restrict__ wq, unsigned short* __restrict__ qkvT) {
    __shared__ __align__(16) char smem[65536];
    char* Asm = smem;
    char* Bsm = smem + 32768;
    int t = threadIdx.x, l = t & 63, w = t >> 6;
    int mb = blockIdx.x * 64, nb = blockIdx.y * 64;
    #pragma unroll
    for (int i = 0; i < 8; ++i) {
        int idx = (w * 8 + i) * 64 + l;
        int r = idx >> 5, p = idx & 31;
        gload16(xnT + (size_t)(mb + r) * 256 + ((p ^ (r & 7)) * 8), Asm + (w * 8 + i) * 1024);
    }
    #pragma unroll
    for (int i = 0; i < 8; ++i) {
        int idx = (w * 8 + i) * 64 + l;
        int r = idx >> 5, p = idx & 31;
        gload16(wq + (size_t)(nb + r) * 256 + ((p ^ (r & 7)) * 8), Bsm + (w * 8 + i) * 1024);
    }
    __syncthreads();
    int arow = w * 16 + (l & 15);
    bf16x8 af[8];
    #pragma unroll
    for (int ks = 0; ks < 8; ++ks)
        af[ks] = *(const bf16x8*)(Asm + arow * 512 + (((ks * 4 + (l >> 4)) ^ (arow & 7)) << 4));
    f32x4 acc[4];
    #pragma unroll
    for (int i = 0; i < 4; ++i) acc[i] = f32x4{0.f, 0.f, 0.f, 0.f};
    #pragma unroll
    for (int sub = 0; sub < 4; ++sub) {
        int brow = sub * 16 + (l & 15);
        #pragma unroll
        for (int ks = 0; ks < 8; ++ks) {
            bf16x8 bb = *(const bf16x8*)(Bsm + brow * 512 + (((ks * 4 + (l >> 4)) ^ (brow & 7)) << 4));
            acc[sub] = mfma16(af[ks], bb, acc[sub]);
        }
    }
    int row0 = mb + w * 16 + (l >> 4) * 4;
    #pragma unroll
    for (int sub = 0; sub < 4; ++sub) {
        #pragma unroll
        for (int r = 0; r < 4; ++r)
            qkvT[(size_t)(row0 + r) * 768 + nb + sub * 16 + (l & 15)] = f2bf(acc[sub][r]);
    }
}

// ---------------------------------------------------------------------------
// K4: transpose V from qkvT cols [512,768) (b,n,c) -> vT (b,c,n) bf16
// ---------------------------------------------------------------------------
__global__ __launch_bounds__(256) void k_vtrans(const unsigned short* __restrict__ qkvT,
                                                unsigned short* __restrict__ vT) {
    __shared__ __align__(16) unsigned short tsm[64][72];
    int t = threadIdx.x;
    int nb = blockIdx.x * 64, cb = blockIdx.y * 64, b = blockIdx.z;
    int nl = t >> 2, cc = (t & 3) * 16;
    const unsigned short* src = qkvT + (size_t)(b * 4096 + nb + nl) * 768 + 512 + cb + cc;
    u16x8 v0 = *(const u16x8*)src;
    u16x8 v1 = *(const u16x8*)(src + 8);
    *(u16x8*)&tsm[nl][cc] = v0;
    *(u16x8*)&tsm[nl][cc + 8] = v1;
    __syncthreads();
    int clc = t >> 2, nn = (t & 3) * 16;
    u16x8 o0, o1;
    #pragma unroll
    for (int j = 0; j < 8; ++j) { o0[j] = tsm[nn + j][clc]; o1[j] = tsm[nn + 8 + j][clc]; }
    unsigned short* dst = vT + (size_t)(b * 256 + cb + clc) * 4096 + nb + nn;
    *(u16x8*)dst = o0;
    *(u16x8*)(dst + 8) = o1;
}

// ---------------------------------------------------------------------------
// K5: flash attention, KVBLK=32, 32KB LDS (so 2 blocks/CU can co-reside —
// round-2 evidence: 64KB LDS blocks never co-scheduled). kv-split x2.
// Block = 4 waves, 64 q-rows (16/wave). d=256.
// LDS: K[32][256] @0 (16KB), V^T[256][32] @16KB (16KB); per-wave P (1KB)
// overlaps the dead K region after QK^T. Q pre-scaled by (1/16)*log2(e).
// T13 defer-max: skip O-rescale while tile max <= m_run + 8 (exact online-SM
// invariants preserved: l_run always = sum 2^(s - m_run), O unnormalized by l).
// ---------------------------------------------------------------------------
__global__ __launch_bounds__(256) void k_attn(const unsigned short* __restrict__ qkvT,
        const unsigned short* __restrict__ vT, unsigned short* __restrict__ Opart,
        float* __restrict__ ml) {
    __shared__ __align__(16) char smem[32768];
    char* Ksm = smem;             // [32][256] bf16, rows 512B, chunk-XOR key r&7
    char* Vsm = smem + 16384;     // [256][32] bf16, rows 64B,  chunk-XOR key r&3
    int t = threadIdx.x, l = t & 63, w = t >> 6;
    char* Psm = smem + w * 1024;  // per-wave 16x32 bf16, rows 64B, XOR key r&3
    int b = blockIdx.z;
    int half = blockIdx.y;
    int qb = blockIdx.x * 64;
    int kv0 = half * 2048;

    const unsigned short* qrow =
        qkvT + (size_t)(b * 4096 + qb + w * 16 + (l & 15)) * 768 + (l >> 4) * 8;
    bf16x8 qf[8];
    #pragma unroll
    for (int ks = 0; ks < 8; ++ks) qf[ks] = *(const bf16x8*)(qrow + ks * 32);

    f32x4 acc[16];
    #pragma unroll
    for (int i = 0; i < 16; ++i) acc[i] = f32x4{0.f, 0.f, 0.f, 0.f};
    float m_run[4], l_run[4];
    #pragma unroll
    for (int r = 0; r < 4; ++r) { m_run[r] = -3.0e38f; l_run[r] = 0.f; }

    const unsigned short* kg0 = qkvT + (size_t)(b * 4096) * 768 + 256;
    const unsigned short* vg0 = vT + (size_t)(b * 256) * 4096;

    for (int kv = kv0; kv < kv0 + 2048; kv += 32) {
        __syncthreads();  // prev iter's P/V reads done before restaging
        #pragma unroll
        for (int i = 0; i < 4; ++i) {       // K tile: 16KB, 4 x 1KB per wave
            int e = (w * 4 + i) * 64 + l;
            int r = e >> 5, p = e & 31;
            gload16(kg0 + (size_t)(kv + r) * 768 + ((p ^ (r & 7)) * 8), Ksm + (w * 4 + i) * 1024);
        }
        #pragma unroll
        for (int i = 0; i < 4; ++i) {       // V tile: 16KB
            int e = (w * 4 + i) * 64 + l;
            int r = e >> 2, p = e & 3;
            gload16(vg0 + (size_t)r * 4096 + kv + ((p ^ (r & 3)) * 8), Vsm + (w * 4 + i) * 1024);
        }
        __syncthreads();  // staging visible

        // S = Q·K^T (log2 domain)
        f32x4 s[2];
        #pragma unroll
        for (int jt = 0; jt < 2; ++jt) {
            f32x4 a = f32x4{0.f, 0.f, 0.f, 0.f};
            int jr = jt * 16 + (l & 15);
            #pragma unroll
            for (int ks = 0; ks < 8; ++ks) {
                bf16x8 kb = *(const bf16x8*)(Ksm + jr * 512 + (((ks * 4 + (l >> 4)) ^ (jr & 7)) << 4));
                a = mfma16(qf[ks], kb, a);
            }
            s[jt] = a;
        }

        // online softmax, deferred-max (THR=8 in log2 domain -> p <= 256)
        float tm[4];
        #pragma unroll
        for (int r = 0; r < 4; ++r) {
            float v = fmaxf(s[0][r], s[1][r]);
            #pragma unroll
            for (int mm = 1; mm < 16; mm <<= 1) v = fmaxf(v, __shfl_xor(v, mm));
            tm[r] = v;
        }
        int defer = 1;
        #pragma unroll
        for (int r = 0; r < 4; ++r) defer &= (tm[r] <= m_run[r] + 8.f) ? 1 : 0;
        bool alldef = __all(defer);
        float sf[4];
        if (!alldef) {
            #pragma unroll
            for (int r = 0; r < 4; ++r) {
                float mn = fmaxf(m_run[r], tm[r]);
                sf[r] = __builtin_amdgcn_exp2f(m_run[r] - mn);
                m_run[r] = mn;
            }
        }
        float p[2][4];
        float rs[4] = {0.f, 0.f, 0.f, 0.f};
        #pragma unroll
        for (int jt = 0; jt < 2; ++jt) {
            #pragma unroll
            for (int r = 0; r < 4; ++r) {
                float pv = __builtin_amdgcn_exp2f(s[jt][r] - m_run[r]);
                p[jt][r] = pv;
                rs[r] += pv;
            }
        }
        #pragma unroll
        for (int r = 0; r < 4; ++r) {
            float tsum = rs[r];
            #pragma unroll
            for (int mm = 1; mm < 16; mm <<= 1) tsum += __shfl_xor(tsum, mm);
            rs[r] = tsum;
        }
        if (alldef) {
            #pragma unroll
            for (int r = 0; r < 4; ++r) l_run[r] += rs[r];
        } else {
            #pragma unroll
            for (int r = 0; r < 4; ++r) l_run[r] = l_run[r] * sf[r] + rs[r];
            #pragma unroll
            for (int i = 0; i < 16; ++i) {
                acc[i][0] *= sf[0]; acc[i][1] *= sf[1]; acc[i][2] *= sf[2]; acc[i][3] *= sf[3];
            }
        }

        __syncthreads();  // all waves done reading K -> safe to write P over K region

        #pragma unroll
        for (int jt = 0; jt < 2; ++jt) {
            #pragma unroll
            for (int r = 0; r < 4; ++r) {
                int row = (l >> 4) * 4 + r;
                int j16 = jt * 16 + (l & 15);
                int byteoff = row * 64 + (((j16 >> 3) ^ (row & 3)) << 4) + (j16 & 7) * 2;
                *(unsigned short*)(Psm + byteoff) = f2bf(p[jt][r]);
            }
        }
        asm volatile("s_waitcnt lgkmcnt(0)" ::: "memory");
        __builtin_amdgcn_sched_barrier(0);

        // O += P · V  (single K=32 step)
        {
            int pr = l & 15;
            bf16x8 pa = *(const bf16x8*)(Psm + pr * 64 + (((l >> 4) ^ (pr & 3)) << 4));
            #pragma unroll
            for (int sub = 0; sub < 16; ++sub) {
                int cr = sub * 16 + (l & 15);
                bf16x8 vb = *(const bf16x8*)(Vsm + cr * 64 + (((l >> 4) ^ (cr & 3)) << 4));
                acc[sub] = mfma16(pa, vb, acc[sub]);
            }
        }
    }

    float inv[4];
    #pragma unroll
    for (int r = 0; r < 4; ++r) inv[r] = 1.f / l_run[r];
    unsigned short* orow = Opart + (size_t)half * 16384 * 256 +
                           (size_t)(b * 4096 + qb + w * 16) * 256;
    #pragma unroll
    for (int sub = 0; sub < 16; ++sub) {
        #pragma unroll
        for (int r = 0; r < 4; ++r)
            orow[(size_t)((l >> 4) * 4 + r) * 256 + sub * 16 + (l & 15)] = f2bf(acc[sub][r] * inv[r]);
    }
    if ((l & 15) == 0) {
        size_t mlbase = (size_t)(b * 4096 + qb + w * 16 + (l >> 4) * 4) * 4;
        #pragma unroll
        for (int r = 0; r < 4; ++r) {
            ml[mlbase + (size_t)r * 4 + half * 2]     = m_run[r];
            ml[mlbase + (size_t)r * 4 + half * 2 + 1] = l_run[r];
        }
    }
}

// ---------------------------------------------------------------------------
// K5b: combine the two kv-halves: O = w1*O1 + w2*O2, wi = 2^(mi-m) * li / Z.
// ---------------------------------------------------------------------------
__global__ __launch_bounds__(256) void k_combine(const unsigned short* __restrict__ Opart,
        const float* __restrict__ ml, unsigned short* __restrict__ Ot) {
    int gid = blockIdx.x * 256 + threadIdx.x;   // 524288 threads: row = gid>>5, 8 cols each
    int row = gid >> 5;
    int c0 = (gid & 31) * 8;
    float m1 = ml[row * 4], l1 = ml[row * 4 + 1];
    float m2 = ml[row * 4 + 2], l2 = ml[row * 4 + 3];
    float m = fmaxf(m1, m2);
    float a1 = __builtin_amdgcn_exp2f(m1 - m) * l1;
    float a2 = __builtin_amdgcn_exp2f(m2 - m) * l2;
    float inv = 1.f / (a1 + a2);
    float w1 = a1 * inv, w2 = a2 * inv;
    size_t off = (size_t)row * 256 + c0;
    u16x8 o1 = *(const u16x8*)(Opart + off);
    u16x8 o2 = *(const u16x8*)(Opart + (size_t)16384 * 256 + off);
    u16x8 o;
    #pragma unroll
    for (int j = 0; j < 8; ++j) o[j] = f2bf(w1 * bf2f(o1[j]) + w2 * bf2f(o2[j]));
    *(u16x8*)(Ot + off) = o;
}

// ---------------------------------------------------------------------------
// K6: proj GEMM + bias + residual. out(b,c,n) = w_proj @ attn_out + b_proj + xn.
// ---------------------------------------------------------------------------
__global__ __launch_bounds__(256) void k_proj(const unsigned short* __restrict__ Ot,
        const unsigned short* __restrict__ wp, const float* __restrict__ bproj,
        const float* __restrict__ xn, float* __restrict__ out) {
    __shared__ __align__(16) char smem[65536];
    char* Asm = smem;
    char* Bsm = smem + 32768;
    int t = threadIdx.x, l = t & 63, w = t >> 6;
    int mb = blockIdx.x * 64, nb = blockIdx.y * 64;
    #pragma unroll
    for (int i = 0; i < 8; ++i) {
        int idx = (w * 8 + i) * 64 + l;
        int r = idx >> 5, p = idx & 31;
        gload16(Ot + (size_t)(mb + r) * 256 + ((p ^ (r & 7)) * 8), Asm + (w * 8 + i) * 1024);
    }
    #pragma unroll
    for (int i = 0; i < 8; ++i) {
        int idx = (w * 8 + i) * 64 + l;
        int r = idx >> 5, p = idx & 31;
        gload16(wp + (size_t)(nb + r) * 256 + ((p ^ (r & 7)) * 8), Bsm + (w * 8 + i) * 1024);
    }
    __syncthreads();
    int arow = w * 16 + (l & 15);
    bf16x8 af[8];
    #pragma unroll
    for (int ks = 0; ks < 8; ++ks)
        af[ks] = *(const bf16x8*)(Asm + arow * 512 + (((ks * 4 + (l >> 4)) ^ (arow & 7)) << 4));
    f32x4 acc[4];
    #pragma unroll
    for (int i = 0; i < 4; ++i) acc[i] = f32x4{0.f, 0.f, 0.f, 0.f};
    #pragma unroll
    for (int sub = 0; sub < 4; ++sub) {
        int brow = sub * 16 + (l & 15);
        #pragma unroll
        for (int ks = 0; ks < 8; ++ks) {
            bf16x8 bb = *(const bf16x8*)(Bsm + brow * 512 + (((ks * 4 + (l >> 4)) ^ (brow & 7)) << 4));
            acc[sub] = mfma16(af[ks], bb, acc[sub]);
        }
    }
    __syncthreads();  // all waves done reading A/B tiles; reuse LDS for transpose
    float* tr = (float*)smem;  // [64][68] f32
    #pragma unroll
    for (int sub = 0; sub < 4; ++sub) {
        int o = sub * 16 + (l & 15);
        *(f32x4*)(tr + o * 68 + w * 16 + (l >> 4) * 4) = acc[sub];
    }
    __syncthreads();
    int b = mb >> 12;
    int nloc = mb & 4095;
    #pragma unroll
    for (int it = 0; it < 4; ++it) {
        int e = it * 256 + t;
        int o = e >> 4, m4 = (e & 15) * 4;
        f32x4 v = *(const f32x4*)(tr + o * 68 + m4);
        float bv = bproj[nb + o];
        size_t off = ((size_t)(b * 256 + nb + o)) * 4096 + nloc + m4;
        float4 xx = *(const float4*)(xn + off);
        float4 ov;
        ov.x = v[0] + bv + xx.x;
        ov.y = v[1] + bv + xx.y;
        ov.z = v[2] + bv + xx.z;
        ov.w = v[3] + bv + xx.w;
        *(float4*)(out + off) = ov;
    }
}

// ---------------------------------------------------------------------------
extern "C" void kernel_launch(void* const* d_in, const int* in_sizes, int n_in,
                              void* d_out, int out_size, void* d_ws, size_t ws_size,
                              hipStream_t stream) {
    const float* x      = (const float*)d_in[0];
    const float* nscale = (const float*)d_in[1];
    const float* nbias  = (const float*)d_in[2];
    const float* wqkv   = (const float*)d_in[3];
    const float* wproj  = (const float*)d_in[4];
    const float* bproj  = (const float*)d_in[5];
    float* out = (float*)d_out;

    char* ws = (char*)d_ws;
    float* stats = (float*)ws;                                        // 1 KB
    float* xn    = (float*)(ws + 4096);                               // 16 MB fp32 (b,c,n)
    unsigned short* xnT = (unsigned short*)(ws + 4096 + 16777216);    // 8 MB bf16 (b,n,c)
    unsigned short* wq  = (unsigned short*)(ws + 4096 + 16777216 + 8388608);  // 384 KB
    unsigned short* wp  = wq + 768 * 256;                             // 128 KB
    unsigned short* qkvT = wp + 256 * 256;                            // 24 MB bf16 (b,n,768)
    unsigned short* vT   = qkvT + (size_t)16384 * 768;                // 8 MB bf16 (b,c,n)
    unsigned short* Opart = vT + (size_t)4 * 256 * 4096;              // 16 MB bf16 (2,16384,256)
    float* ml = (float*)(Opart + (size_t)2 * 16384 * 256);            // 256 KB
    unsigned short* Ot   = xnT;  // alias: xnT dead after k_qkv

    hipLaunchKernelGGL(k_wconv,   dim3(1024),       dim3(256), 0, stream, wqkv, wproj, wq, wp);
    hipLaunchKernelGGL(k_gnstats, dim3(128),        dim3(256), 0, stream, x, stats);
    hipLaunchKernelGGL(k_gnapply, dim3(64, 4, 4),   dim3(256), 0, stream, x, nscale, nbias, stats, xn, xnT);
    hipLaunchKernelGGL(k_qkv,     dim3(256, 12),    dim3(256), 0, stream, xnT, wq, qkvT);
    hipLaunchKernelGGL(k_vtrans,  dim3(64, 4, 4),   dim3(256), 0, stream, qkvT, vT);
    hipLaunchKernelGGL(k_attn,    dim3(64, 2, 4),   dim3(256), 0, stream, qkvT, vT, Opart, ml);
    hipLaunchKernelGGL(k_combine, dim3(2048),       dim3(256), 0, stream, Opart, ml, Ot);
    hipLaunchKernelGGL(k_proj,    dim3(256, 4),     dim3(256), 0, stream, Ot, wp, bproj, xn, out);
}

// Round 4
// 187.162 us; speedup vs baseline: 1.7850x; 1.7850x over previous
//
#include <hip/hip_runtime.h>
#include <cstdint>
#include <cstddef>

typedef __bf16 bf16;
typedef __attribute__((ext_vector_type(8))) __bf16 bf16x8;
typedef __attribute__((ext_vector_type(4))) float f32x4;
typedef __attribute__((ext_vector_type(4))) unsigned short u16x4;
typedef __attribute__((ext_vector_type(8))) unsigned short u16x8;

#define DEV __device__ __forceinline__

// fp32 -> bf16 round-to-nearest-even (explicit, deterministic)
DEV unsigned short f2bf(float f) {
    unsigned int u = __builtin_bit_cast(unsigned int, f);
    u += 0x7FFFu + ((u >> 16) & 1u);
    return (unsigned short)(u >> 16);
}

DEV float bf2f(unsigned short h) {
    unsigned int u = ((unsigned int)h) << 16;
    return __builtin_bit_cast(float, u);
}

// async global->LDS, 16B per lane; lds base must be wave-uniform (HW adds lane*16)
DEV void gload16(const void* g, void* l) {
    __builtin_amdgcn_global_load_lds(
        (const __attribute__((address_space(1))) unsigned int*)g,
        (__attribute__((address_space(3))) unsigned int*)l, 16, 0, 0);
}

DEV f32x4 mfma16(bf16x8 a, bf16x8 b, f32x4 c) {
    return __builtin_amdgcn_mfma_f32_16x16x32_bf16(a, b, c, 0, 0, 0);
}

// ---------------------------------------------------------------------------
// K0: weight conversion. q-rows of w_qkv get softmax scale (1/16) * log2(e)
// folded in, so attention logits are already in log2 domain.
// ---------------------------------------------------------------------------
__global__ void k_wconv(const float* __restrict__ wqkv, const float* __restrict__ wproj,
                        unsigned short* __restrict__ wq, unsigned short* __restrict__ wp) {
    int i = blockIdx.x * 256 + threadIdx.x;   // grid covers 768*256 + 256*256 exactly
    if (i < 768 * 256) {
        float v = wqkv[i];
        if (i < 256 * 256) v *= 0.09016844005556022f;  // (1/16)*log2(e)
        wq[i] = f2bf(v);
    } else {
        int j = i - 768 * 256;
        wp[j] = f2bf(wproj[j]);
    }
}

// ---------------------------------------------------------------------------
// K1: GroupNorm stats. One block per (b, group): 8 channels * 4096 = 32768 f32.
// ---------------------------------------------------------------------------
__global__ __launch_bounds__(256) void k_gnstats(const float* __restrict__ x,
                                                 float* __restrict__ stats) {
    int bg = blockIdx.x;  // b*32 + g
    const float4* xp = (const float4*)(x + (size_t)bg * 32768);
    int t = threadIdx.x;
    float s = 0.f, sq = 0.f;
    #pragma unroll 4
    for (int i = 0; i < 32; ++i) {
        float4 v = xp[t + i * 256];
        s  += v.x + v.y + v.z + v.w;
        sq += v.x * v.x + v.y * v.y + v.z * v.z + v.w * v.w;
    }
    #pragma unroll
    for (int m = 1; m < 64; m <<= 1) { s += __shfl_xor(s, m); sq += __shfl_xor(sq, m); }
    __shared__ float red[8];
    int w = t >> 6;
    if ((t & 63) == 0) { red[w] = s; red[4 + w] = sq; }
    __syncthreads();
    if (t == 0) {
        s  = red[0] + red[1] + red[2] + red[3];
        sq = red[4] + red[5] + red[6] + red[7];
        float mean = s * (1.f / 32768.f);
        float var  = sq * (1.f / 32768.f) - mean * mean;
        stats[bg * 2]     = mean;
        stats[bg * 2 + 1] = rsqrtf(var + 1e-5f);
    }
}

// ---------------------------------------------------------------------------
// K2: apply GroupNorm -> xn fp32 (b,c,n) [residual] + xnT bf16 (b,n,c) [GEMM A]
// ---------------------------------------------------------------------------
__global__ __launch_bounds__(256) void k_gnapply(const float* __restrict__ x,
        const float* __restrict__ scale, const float* __restrict__ bias,
        const float* __restrict__ stats, float* __restrict__ xn,
        unsigned short* __restrict__ xnT) {
    __shared__ __align__(16) unsigned short tsm[64][72];
    int t = threadIdx.x;
    int nb = blockIdx.x * 64, cb = blockIdx.y * 64, b = blockIdx.z;
    int cl = t >> 2, nc = (t & 3) * 16;
    int cg = cb + cl;
    float mean = stats[(b * 32 + (cg >> 3)) * 2];
    float rstd = stats[(b * 32 + (cg >> 3)) * 2 + 1];
    float sc = scale[cg] * rstd;
    float bi = bias[cg] - mean * sc;      // xn = x*sc + bi
    const float4* xrow = (const float4*)(x  + ((size_t)(b * 256 + cg)) * 4096 + nb + nc);
    float4*      orow  = (float4*)      (xn + ((size_t)(b * 256 + cg)) * 4096 + nb + nc);
    #pragma unroll
    for (int j = 0; j < 4; ++j) {
        float4 v = xrow[j];
        v.x = v.x * sc + bi; v.y = v.y * sc + bi; v.z = v.z * sc + bi; v.w = v.w * sc + bi;
        orow[j] = v;
        u16x4 us;
        us[0] = f2bf(v.x); us[1] = f2bf(v.y); us[2] = f2bf(v.z); us[3] = f2bf(v.w);
        *(u16x4*)&tsm[cl][nc + j * 4] = us;
    }
    __syncthreads();
    int nl = t >> 2, cc = (t & 3) * 16;
    u16x8 o0, o1;
    #pragma unroll
    for (int j = 0; j < 8; ++j) { o0[j] = tsm[cc + j][nl]; o1[j] = tsm[cc + 8 + j][nl]; }
    unsigned short* dst = xnT + ((size_t)(b * 4096 + nb + nl)) * 256 + cb + cc;
    *(u16x8*)dst = o0;
    *(u16x8*)(dst + 8) = o1;
}

// ---------------------------------------------------------------------------
// K3: QKV GEMM. qkvT(16384, 768) = xnT(16384,256) @ w_qkv^T.  64x64 tile, K=256.
// ---------------------------------------------------------------------------
__global__ __launch_bounds__(256) void k_qkv(const unsigned short* __restrict__ xnT,
        const unsigned short* __restrict__ wq, unsigned short* __restrict__ qkvT) {
    __shared__ __align__(16) char smem[65536];
    char* Asm = smem;
    char* Bsm = smem + 32768;
    int t = threadIdx.x, l = t & 63, w = t >> 6;
    int mb = blockIdx.x * 64, nb = blockIdx.y * 64;
    #pragma unroll
    for (int i = 0; i < 8; ++i) {
        int idx = (w * 8 + i) * 64 + l;
        int r = idx >> 5, p = idx & 31;
        gload16(xnT + (size_t)(mb + r) * 256 + ((p ^ (r & 7)) * 8), Asm + (w * 8 + i) * 1024);
    }
    #pragma unroll
    for (int i = 0; i < 8; ++i) {
        int idx = (w * 8 + i) * 64 + l;
        int r = idx >> 5, p = idx & 31;
        gload16(wq + (size_t)(nb + r) * 256 + ((p ^ (r & 7)) * 8), Bsm + (w * 8 + i) * 1024);
    }
    __syncthreads();
    int arow = w * 16 + (l & 15);
    bf16x8 af[8];
    #pragma unroll
    for (int ks = 0; ks < 8; ++ks)
        af[ks] = *(const bf16x8*)(Asm + arow * 512 + (((ks * 4 + (l >> 4)) ^ (arow & 7)) << 4));
    f32x4 acc[4];
    #pragma unroll
    for (int i = 0; i < 4; ++i) acc[i] = f32x4{0.f, 0.f, 0.f, 0.f};
    #pragma unroll
    for (int sub = 0; sub < 4; ++sub) {
        int brow = sub * 16 + (l & 15);
        #pragma unroll
        for (int ks = 0; ks < 8; ++ks) {
            bf16x8 bb = *(const bf16x8*)(Bsm + brow * 512 + (((ks * 4 + (l >> 4)) ^ (brow & 7)) << 4));
            acc[sub] = mfma16(af[ks], bb, acc[sub]);
        }
    }
    int row0 = mb + w * 16 + (l >> 4) * 4;
    #pragma unroll
    for (int sub = 0; sub < 4; ++sub) {
        #pragma unroll
        for (int r = 0; r < 4; ++r)
            qkvT[(size_t)(row0 + r) * 768 + nb + sub * 16 + (l & 15)] = f2bf(acc[sub][r]);
    }
}

// ---------------------------------------------------------------------------
// K4: transpose V from qkvT cols [512,768) (b,n,c) -> vT (b,c,n) bf16
// ---------------------------------------------------------------------------
__global__ __launch_bounds__(256) void k_vtrans(const unsigned short* __restrict__ qkvT,
                                                unsigned short* __restrict__ vT) {
    __shared__ __align__(16) unsigned short tsm[64][72];
    int t = threadIdx.x;
    int nb = blockIdx.x * 64, cb = blockIdx.y * 64, b = blockIdx.z;
    int nl = t >> 2, cc = (t & 3) * 16;
    const unsigned short* src = qkvT + (size_t)(b * 4096 + nb + nl) * 768 + 512 + cb + cc;
    u16x8 v0 = *(const u16x8*)src;
    u16x8 v1 = *(const u16x8*)(src + 8);
    *(u16x8*)&tsm[nl][cc] = v0;
    *(u16x8*)&tsm[nl][cc + 8] = v1;
    __syncthreads();
    int clc = t >> 2, nn = (t & 3) * 16;
    u16x8 o0, o1;
    #pragma unroll
    for (int j = 0; j < 8; ++j) { o0[j] = tsm[nn + j][clc]; o1[j] = tsm[nn + 8 + j][clc]; }
    unsigned short* dst = vT + (size_t)(b * 256 + cb + clc) * 4096 + nb + nn;
    *(u16x8*)dst = o0;
    *(u16x8*)(dst + 8) = o1;
}

// ---------------------------------------------------------------------------
// K5: flash attention. 512 threads = 8 waves, QBLK=128 (16 q-rows/wave),
// KVBLK=64, kv-split x2. Grid = 256 blocks, 1 block/CU (R2/R3 evidence: only
// 1 block/CU ever co-resides, so TLP comes from 2 waves/SIMD inside a block).
// XCD decode: combo = bid&7 -> (b, half), so under id%8 XCD round-robin every
// block on an XCD shares one (batch, kv-half) -> 2MB K/V slice L2-resident.
// LDS: K[64][256] @0 (32KB), V^T[256][64] @32KB; per-wave P (2KB x 8 = 16KB)
// overlaps the dead K region after QK^T. Q pre-scaled by (1/16)*log2(e).
// T13 defer-max: skip O-rescale while tile max <= m_run + 8.
// ---------------------------------------------------------------------------
__global__ __launch_bounds__(512, 2) void k_attn(const unsigned short* __restrict__ qkvT,
        const unsigned short* __restrict__ vT, unsigned short* __restrict__ Opart,
        float* __restrict__ ml) {
    __shared__ __align__(16) char smem[65536];
    char* Ksm = smem;
    char* Vsm = smem + 32768;
    int t = threadIdx.x, l = t & 63, w = t >> 6;   // w in 0..7
    char* Psm = smem + w * 2048;   // per-wave, overlaps K region
    int bid = blockIdx.x;
    int combo = bid & 7;
    int b = combo >> 1;
    int half = combo & 1;
    int qb = (bid >> 3) * 128;
    int kv0 = half * 2048;

    const unsigned short* qrow =
        qkvT + (size_t)(b * 4096 + qb + w * 16 + (l & 15)) * 768 + (l >> 4) * 8;
    bf16x8 qf[8];
    #pragma unroll
    for (int ks = 0; ks < 8; ++ks) qf[ks] = *(const bf16x8*)(qrow + ks * 32);

    f32x4 acc[16];
    #pragma unroll
    for (int i = 0; i < 16; ++i) acc[i] = f32x4{0.f, 0.f, 0.f, 0.f};
    float m_run[4], l_run[4];
    #pragma unroll
    for (int r = 0; r < 4; ++r) { m_run[r] = -3.0e38f; l_run[r] = 0.f; }

    const unsigned short* kg0 = qkvT + (size_t)(b * 4096) * 768 + 256;
    const unsigned short* vg0 = vT + (size_t)(b * 256) * 4096;

    for (int kv = kv0; kv < kv0 + 2048; kv += 64) {
        __syncthreads();  // prev iter's P/V reads done before restaging
        #pragma unroll
        for (int i = 0; i < 4; ++i) {       // K tile: 32 x 1KB chunks, 4/wave
            int e = (w * 4 + i) * 64 + l;
            int r = e >> 5, p = e & 31;
            gload16(kg0 + (size_t)(kv + r) * 768 + ((p ^ (r & 7)) * 8), Ksm + (w * 4 + i) * 1024);
        }
        #pragma unroll
        for (int i = 0; i < 4; ++i) {       // V tile: 32 x 1KB chunks, 4/wave
            int e = (w * 4 + i) * 64 + l;
            int r = e >> 3, p = e & 7;
            gload16(vg0 + (size_t)r * 4096 + kv + ((p ^ (r & 7)) * 8), Vsm + (w * 4 + i) * 1024);
        }
        __syncthreads();  // staging visible

        // S = Q·K^T (log2 domain)
        f32x4 s[4];
        #pragma unroll
        for (int jt = 0; jt < 4; ++jt) {
            f32x4 a = f32x4{0.f, 0.f, 0.f, 0.f};
            int jr = jt * 16 + (l & 15);
            #pragma unroll
            for (int ks = 0; ks < 8; ++ks) {
                bf16x8 kb = *(const bf16x8*)(Ksm + jr * 512 + (((ks * 4 + (l >> 4)) ^ (jr & 7)) << 4));
                a = mfma16(qf[ks], kb, a);
            }
            s[jt] = a;
        }

        // online softmax, deferred-max (THR=8 in log2 domain -> p <= 256)
        float tm[4];
        #pragma unroll
        for (int r = 0; r < 4; ++r) {
            float v = fmaxf(fmaxf(s[0][r], s[1][r]), fmaxf(s[2][r], s[3][r]));
            #pragma unroll
            for (int mm = 1; mm < 16; mm <<= 1) v = fmaxf(v, __shfl_xor(v, mm));
            tm[r] = v;
        }
        int defer = 1;
        #pragma unroll
        for (int r = 0; r < 4; ++r) defer &= (tm[r] <= m_run[r] + 8.f) ? 1 : 0;
        bool alldef = __all(defer);
        float sf[4];
        if (!alldef) {
            #pragma unroll
            for (int r = 0; r < 4; ++r) {
                float mn = fmaxf(m_run[r], tm[r]);
                sf[r] = __builtin_amdgcn_exp2f(m_run[r] - mn);
                m_run[r] = mn;
            }
        }
        float p[4][4];
        float rs[4] = {0.f, 0.f, 0.f, 0.f};
        #pragma unroll
        for (int jt = 0; jt < 4; ++jt) {
            #pragma unroll
            for (int r = 0; r < 4; ++r) {
                float pv = __builtin_amdgcn_exp2f(s[jt][r] - m_run[r]);
                p[jt][r] = pv;
                rs[r] += pv;
            }
        }
        #pragma unroll
        for (int r = 0; r < 4; ++r) {
            float tsum = rs[r];
            #pragma unroll
            for (int mm = 1; mm < 16; mm <<= 1) tsum += __shfl_xor(tsum, mm);
            rs[r] = tsum;
        }
        if (alldef) {
            #pragma unroll
            for (int r = 0; r < 4; ++r) l_run[r] += rs[r];
        } else {
            #pragma unroll
            for (int r = 0; r < 4; ++r) l_run[r] = l_run[r] * sf[r] + rs[r];
            #pragma unroll
            for (int i = 0; i < 16; ++i) {
                acc[i][0] *= sf[0]; acc[i][1] *= sf[1]; acc[i][2] *= sf[2]; acc[i][3] *= sf[3];
            }
        }

        __syncthreads();  // all waves done reading K -> safe to write P over K region

        #pragma unroll
        for (int jt = 0; jt < 4; ++jt) {
            #pragma unroll
            for (int r = 0; r < 4; ++r) {
                int row = (l >> 4) * 4 + r;
                int j = jt * 16 + (l & 15);
                int byteoff = row * 128 + (((j >> 3) ^ (row & 7)) << 4) + (j & 7) * 2;
                *(unsigned short*)(Psm + byteoff) = f2bf(p[jt][r]);
            }
        }
        asm volatile("s_waitcnt lgkmcnt(0)" ::: "memory");
        __builtin_amdgcn_sched_barrier(0);

        // O += P · V
        #pragma unroll
        for (int js = 0; js < 2; ++js) {
            int pr = l & 15;
            bf16x8 pa = *(const bf16x8*)(Psm + pr * 128 + (((js * 4 + (l >> 4)) ^ (pr & 7)) << 4));
            #pragma unroll
            for (int sub = 0; sub < 16; ++sub) {
                int cr = sub * 16 + (l & 15);
                bf16x8 vb = *(const bf16x8*)(Vsm + cr * 128 + (((js * 4 + (l >> 4)) ^ (cr & 7)) << 4));
                acc[sub] = mfma16(pa, vb, acc[sub]);
            }
        }
    }

    float inv[4];
    #pragma unroll
    for (int r = 0; r < 4; ++r) inv[r] = 1.f / l_run[r];
    unsigned short* orow = Opart + (size_t)half * 16384 * 256 +
                           (size_t)(b * 4096 + qb + w * 16) * 256;
    #pragma unroll
    for (int sub = 0; sub < 16; ++sub) {
        #pragma unroll
        for (int r = 0; r < 4; ++r)
            orow[(size_t)((l >> 4) * 4 + r) * 256 + sub * 16 + (l & 15)] = f2bf(acc[sub][r] * inv[r]);
    }
    if ((l & 15) == 0) {
        size_t mlbase = (size_t)(b * 4096 + qb + w * 16 + (l >> 4) * 4) * 4;
        #pragma unroll
        for (int r = 0; r < 4; ++r) {
            ml[mlbase + (size_t)r * 4 + half * 2]     = m_run[r];
            ml[mlbase + (size_t)r * 4 + half * 2 + 1] = l_run[r];
        }
    }
}

// ---------------------------------------------------------------------------
// K5b: combine the two kv-halves: O = w1*O1 + w2*O2, wi = 2^(mi-m) * li / Z.
// ---------------------------------------------------------------------------
__global__ __launch_bounds__(256) void k_combine(const unsigned short* __restrict__ Opart,
        const float* __restrict__ ml, unsigned short* __restrict__ Ot) {
    int gid = blockIdx.x * 256 + threadIdx.x;   // 524288 threads: row = gid>>5, 8 cols each
    int row = gid >> 5;
    int c0 = (gid & 31) * 8;
    float m1 = ml[row * 4], l1 = ml[row * 4 + 1];
    float m2 = ml[row * 4 + 2], l2 = ml[row * 4 + 3];
    float m = fmaxf(m1, m2);
    float a1 = __builtin_amdgcn_exp2f(m1 - m) * l1;
    float a2 = __builtin_amdgcn_exp2f(m2 - m) * l2;
    float inv = 1.f / (a1 + a2);
    float w1 = a1 * inv, w2 = a2 * inv;
    size_t off = (size_t)row * 256 + c0;
    u16x8 o1 = *(const u16x8*)(Opart + off);
    u16x8 o2 = *(const u16x8*)(Opart + (size_t)16384 * 256 + off);
    u16x8 o;
    #pragma unroll
    for (int j = 0; j < 8; ++j) o[j] = f2bf(w1 * bf2f(o1[j]) + w2 * bf2f(o2[j]));
    *(u16x8*)(Ot + off) = o;
}

// ---------------------------------------------------------------------------
// K6: proj GEMM + bias + residual. out(b,c,n) = w_proj @ attn_out + b_proj + xn.
// ---------------------------------------------------------------------------
__global__ __launch_bounds__(256) void k_proj(const unsigned short* __restrict__ Ot,
        const unsigned short* __restrict__ wp, const float* __restrict__ bproj,
        const float* __restrict__ xn, float* __restrict__ out) {
    __shared__ __align__(16) char smem[65536];
    char* Asm = smem;
    char* Bsm = smem + 32768;
    int t = threadIdx.x, l = t & 63, w = t >> 6;
    int mb = blockIdx.x * 64, nb = blockIdx.y * 64;
    #pragma unroll
    for (int i = 0; i < 8; ++i) {
        int idx = (w * 8 + i) * 64 + l;
        int r = idx >> 5, p = idx & 31;
        gload16(Ot + (size_t)(mb + r) * 256 + ((p ^ (r & 7)) * 8), Asm + (w * 8 + i) * 1024);
    }
    #pragma unroll
    for (int i = 0; i < 8; ++i) {
        int idx = (w * 8 + i) * 64 + l;
        int r = idx >> 5, p = idx & 31;
        gload16(wp + (size_t)(nb + r) * 256 + ((p ^ (r & 7)) * 8), Bsm + (w * 8 + i) * 1024);
    }
    __syncthreads();
    int arow = w * 16 + (l & 15);
    bf16x8 af[8];
    #pragma unroll
    for (int ks = 0; ks < 8; ++ks)
        af[ks] = *(const bf16x8*)(Asm + arow * 512 + (((ks * 4 + (l >> 4)) ^ (arow & 7)) << 4));
    f32x4 acc[4];
    #pragma unroll
    for (int i = 0; i < 4; ++i) acc[i] = f32x4{0.f, 0.f, 0.f, 0.f};
    #pragma unroll
    for (int sub = 0; sub < 4; ++sub) {
        int brow = sub * 16 + (l & 15);
        #pragma unroll
        for (int ks = 0; ks < 8; ++ks) {
            bf16x8 bb = *(const bf16x8*)(Bsm + brow * 512 + (((ks * 4 + (l >> 4)) ^ (brow & 7)) << 4));
            acc[sub] = mfma16(af[ks], bb, acc[sub]);
        }
    }
    __syncthreads();  // all waves done reading A/B tiles; reuse LDS for transpose
    float* tr = (float*)smem;  // [64][68] f32
    #pragma unroll
    for (int sub = 0; sub < 4; ++sub) {
        int o = sub * 16 + (l & 15);
        *(f32x4*)(tr + o * 68 + w * 16 + (l >> 4) * 4) = acc[sub];
    }
    __syncthreads();
    int b = mb >> 12;
    int nloc = mb & 4095;
    #pragma unroll
    for (int it = 0; it < 4; ++it) {
        int e = it * 256 + t;
        int o = e >> 4, m4 = (e & 15) * 4;
        f32x4 v = *(const f32x4*)(tr + o * 68 + m4);
        float bv = bproj[nb + o];
        size_t off = ((size_t)(b * 256 + nb + o)) * 4096 + nloc + m4;
        float4 xx = *(const float4*)(xn + off);
        float4 ov;
        ov.x = v[0] + bv + xx.x;
        ov.y = v[1] + bv + xx.y;
        ov.z = v[2] + bv + xx.z;
        ov.w = v[3] + bv + xx.w;
        *(float4*)(out + off) = ov;
    }
}

// ---------------------------------------------------------------------------
extern "C" void kernel_launch(void* const* d_in, const int* in_sizes, int n_in,
                              void* d_out, int out_size, void* d_ws, size_t ws_size,
                              hipStream_t stream) {
    const float* x      = (const float*)d_in[0];
    const float* nscale = (const float*)d_in[1];
    const float* nbias  = (const float*)d_in[2];
    const float* wqkv   = (const float*)d_in[3];
    const float* wproj  = (const float*)d_in[4];
    const float* bproj  = (const float*)d_in[5];
    float* out = (float*)d_out;

    char* ws = (char*)d_ws;
    float* stats = (float*)ws;                                        // 1 KB
    float* xn    = (float*)(ws + 4096);                               // 16 MB fp32 (b,c,n)
    unsigned short* xnT = (unsigned short*)(ws + 4096 + 16777216);    // 8 MB bf16 (b,n,c)
    unsigned short* wq  = (unsigned short*)(ws + 4096 + 16777216 + 8388608);  // 384 KB
    unsigned short* wp  = wq + 768 * 256;                             // 128 KB
    unsigned short* qkvT = wp + 256 * 256;                            // 24 MB bf16 (b,n,768)
    unsigned short* vT   = qkvT + (size_t)16384 * 768;                // 8 MB bf16 (b,c,n)
    unsigned short* Opart = vT + (size_t)4 * 256 * 4096;              // 16 MB bf16 (2,16384,256)
    float* ml = (float*)(Opart + (size_t)2 * 16384 * 256);            // 256 KB
    unsigned short* Ot   = xnT;  // alias: xnT dead after k_qkv

    hipLaunchKernelGGL(k_wconv,   dim3(1024),       dim3(256), 0, stream, wqkv, wproj, wq, wp);
    hipLaunchKernelGGL(k_gnstats, dim3(128),        dim3(256), 0, stream, x, stats);
    hipLaunchKernelGGL(k_gnapply, dim3(64, 4, 4),   dim3(256), 0, stream, x, nscale, nbias, stats, xn, xnT);
    hipLaunchKernelGGL(k_qkv,     dim3(256, 12),    dim3(256), 0, stream, xnT, wq, qkvT);
    hipLaunchKernelGGL(k_vtrans,  dim3(64, 4, 4),   dim3(256), 0, stream, qkvT, vT);
    hipLaunchKernelGGL(k_attn,    dim3(256),        dim3(512), 0, stream, qkvT, vT, Opart, ml);
    hipLaunchKernelGGL(k_combine, dim3(2048),       dim3(256), 0, stream, Opart, ml, Ot);
    hipLaunchKernelGGL(k_proj,    dim3(256, 4),     dim3(256), 0, stream, Ot, wp, bproj, xn, out);
}

// Round 5
// 163.714 us; speedup vs baseline: 2.0406x; 1.1432x over previous
//
#include <hip/hip_runtime.h>
#include <cstdint>
#include <cstddef>

typedef __bf16 bf16;
typedef __attribute__((ext_vector_type(8))) __bf16 bf16x8;
typedef __attribute__((ext_vector_type(4))) float f32x4;
typedef __attribute__((ext_vector_type(4))) unsigned short u16x4;
typedef __attribute__((ext_vector_type(8))) unsigned short u16x8;

#define DEV __device__ __forceinline__

// fp32 -> bf16 round-to-nearest-even (explicit, deterministic)
DEV unsigned short f2bf(float f) {
    unsigned int u = __builtin_bit_cast(unsigned int, f);
    u += 0x7FFFu + ((u >> 16) & 1u);
    return (unsigned short)(u >> 16);
}

DEV float bf2f(unsigned short h) {
    unsigned int u = ((unsigned int)h) << 16;
    return __builtin_bit_cast(float, u);
}

// async global->LDS, 16B per lane; lds base must be wave-uniform (HW adds lane*16)
DEV void gload16(const void* g, void* l) {
    __builtin_amdgcn_global_load_lds(
        (const __attribute__((address_space(1))) unsigned int*)g,
        (__attribute__((address_space(3))) unsigned int*)l, 16, 0, 0);
}

DEV f32x4 mfma16(bf16x8 a, bf16x8 b, f32x4 c) {
    return __builtin_amdgcn_mfma_f32_16x16x32_bf16(a, b, c, 0, 0, 0);
}

// ---------------------------------------------------------------------------
// K0: weight conversion. q-rows of w_qkv get softmax scale (1/16) * log2(e)
// folded in, so attention logits are already in log2 domain.
// ---------------------------------------------------------------------------
__global__ void k_wconv(const float* __restrict__ wqkv, const float* __restrict__ wproj,
                        unsigned short* __restrict__ wq, unsigned short* __restrict__ wp) {
    int i = blockIdx.x * 256 + threadIdx.x;   // grid covers 768*256 + 256*256 exactly
    if (i < 768 * 256) {
        float v = wqkv[i];
        if (i < 256 * 256) v *= 0.09016844005556022f;  // (1/16)*log2(e)
        wq[i] = f2bf(v);
    } else {
        int j = i - 768 * 256;
        wp[j] = f2bf(wproj[j]);
    }
}

// ---------------------------------------------------------------------------
// K1: GroupNorm stats. One block per (b, group): 8 channels * 4096 = 32768 f32.
// ---------------------------------------------------------------------------
__global__ __launch_bounds__(256) void k_gnstats(const float* __restrict__ x,
                                                 float* __restrict__ stats) {
    int bg = blockIdx.x;  // b*32 + g
    const float4* xp = (const float4*)(x + (size_t)bg * 32768);
    int t = threadIdx.x;
    float s = 0.f, sq = 0.f;
    #pragma unroll 4
    for (int i = 0; i < 32; ++i) {
        float4 v = xp[t + i * 256];
        s  += v.x + v.y + v.z + v.w;
        sq += v.x * v.x + v.y * v.y + v.z * v.z + v.w * v.w;
    }
    #pragma unroll
    for (int m = 1; m < 64; m <<= 1) { s += __shfl_xor(s, m); sq += __shfl_xor(sq, m); }
    __shared__ float red[8];
    int w = t >> 6;
    if ((t & 63) == 0) { red[w] = s; red[4 + w] = sq; }
    __syncthreads();
    if (t == 0) {
        s  = red[0] + red[1] + red[2] + red[3];
        sq = red[4] + red[5] + red[6] + red[7];
        float mean = s * (1.f / 32768.f);
        float var  = sq * (1.f / 32768.f) - mean * mean;
        stats[bg * 2]     = mean;
        stats[bg * 2 + 1] = rsqrtf(var + 1e-5f);
    }
}

// ---------------------------------------------------------------------------
// K2: apply GroupNorm -> xn fp32 (b,c,n) [residual] + xnT bf16 (b,n,c) [GEMM A]
// ---------------------------------------------------------------------------
__global__ __launch_bounds__(256) void k_gnapply(const float* __restrict__ x,
        const float* __restrict__ scale, const float* __restrict__ bias,
        const float* __restrict__ stats, float* __restrict__ xn,
        unsigned short* __restrict__ xnT) {
    __shared__ __align__(16) unsigned short tsm[64][72];
    int t = threadIdx.x;
    int nb = blockIdx.x * 64, cb = blockIdx.y * 64, b = blockIdx.z;
    int cl = t >> 2, nc = (t & 3) * 16;
    int cg = cb + cl;
    float mean = stats[(b * 32 + (cg >> 3)) * 2];
    float rstd = stats[(b * 32 + (cg >> 3)) * 2 + 1];
    float sc = scale[cg] * rstd;
    float bi = bias[cg] - mean * sc;      // xn = x*sc + bi
    const float4* xrow = (const float4*)(x  + ((size_t)(b * 256 + cg)) * 4096 + nb + nc);
    float4*      orow  = (float4*)      (xn + ((size_t)(b * 256 + cg)) * 4096 + nb + nc);
    #pragma unroll
    for (int j = 0; j < 4; ++j) {
        float4 v = xrow[j];
        v.x = v.x * sc + bi; v.y = v.y * sc + bi; v.z = v.z * sc + bi; v.w = v.w * sc + bi;
        orow[j] = v;
        u16x4 us;
        us[0] = f2bf(v.x); us[1] = f2bf(v.y); us[2] = f2bf(v.z); us[3] = f2bf(v.w);
        *(u16x4*)&tsm[cl][nc + j * 4] = us;
    }
    __syncthreads();
    int nl = t >> 2, cc = (t & 3) * 16;
    u16x8 o0, o1;
    #pragma unroll
    for (int j = 0; j < 8; ++j) { o0[j] = tsm[cc + j][nl]; o1[j] = tsm[cc + 8 + j][nl]; }
    unsigned short* dst = xnT + ((size_t)(b * 4096 + nb + nl)) * 256 + cb + cc;
    *(u16x8*)dst = o0;
    *(u16x8*)(dst + 8) = o1;
}

// ---------------------------------------------------------------------------
// K3: QKV GEMM. qkvT(16384, 768) = xnT(16384,256) @ w_qkv^T.  64x64 tile, K=256.
// ---------------------------------------------------------------------------
__global__ __launch_bounds__(256) void k_qkv(const unsigned short* __restrict__ xnT,
        const unsigned short* __restrict__ wq, unsigned short* __restrict__ qkvT) {
    __shared__ __align__(16) char smem[65536];
    char* Asm = smem;
    char* Bsm = smem + 32768;
    int t = threadIdx.x, l = t & 63, w = t >> 6;
    int mb = blockIdx.x * 64, nb = blockIdx.y * 64;
    #pragma unroll
    for (int i = 0; i < 8; ++i) {
        int idx = (w * 8 + i) * 64 + l;
        int r = idx >> 5, p = idx & 31;
        gload16(xnT + (size_t)(mb + r) * 256 + ((p ^ (r & 7)) * 8), Asm + (w * 8 + i) * 1024);
    }
    #pragma unroll
    for (int i = 0; i < 8; ++i) {
        int idx = (w * 8 + i) * 64 + l;
        int r = idx >> 5, p = idx & 31;
        gload16(wq + (size_t)(nb + r) * 256 + ((p ^ (r & 7)) * 8), Bsm + (w * 8 + i) * 1024);
    }
    __syncthreads();
    int arow = w * 16 + (l & 15);
    bf16x8 af[8];
    #pragma unroll
    for (int ks = 0; ks < 8; ++ks)
        af[ks] = *(const bf16x8*)(Asm + arow * 512 + (((ks * 4 + (l >> 4)) ^ (arow & 7)) << 4));
    f32x4 acc[4];
    #pragma unroll
    for (int i = 0; i < 4; ++i) acc[i] = f32x4{0.f, 0.f, 0.f, 0.f};
    #pragma unroll
    for (int sub = 0; sub < 4; ++sub) {
        int brow = sub * 16 + (l & 15);
        #pragma unroll
        for (int ks = 0; ks < 8; ++ks) {
            bf16x8 bb = *(const bf16x8*)(Bsm + brow * 512 + (((ks * 4 + (l >> 4)) ^ (brow & 7)) << 4));
            acc[sub] = mfma16(af[ks], bb, acc[sub]);
        }
    }
    int row0 = mb + w * 16 + (l >> 4) * 4;
    #pragma unroll
    for (int sub = 0; sub < 4; ++sub) {
        #pragma unroll
        for (int r = 0; r < 4; ++r)
            qkvT[(size_t)(row0 + r) * 768 + nb + sub * 16 + (l & 15)] = f2bf(acc[sub][r]);
    }
}

// ---------------------------------------------------------------------------
// K4: transpose V from qkvT cols [512,768) (b,n,c) -> vT (b,c,n) bf16
// ---------------------------------------------------------------------------
__global__ __launch_bounds__(256) void k_vtrans(const unsigned short* __restrict__ qkvT,
                                                unsigned short* __restrict__ vT) {
    __shared__ __align__(16) unsigned short tsm[64][72];
    int t = threadIdx.x;
    int nb = blockIdx.x * 64, cb = blockIdx.y * 64, b = blockIdx.z;
    int nl = t >> 2, cc = (t & 3) * 16;
    const unsigned short* src = qkvT + (size_t)(b * 4096 + nb + nl) * 768 + 512 + cb + cc;
    u16x8 v0 = *(const u16x8*)src;
    u16x8 v1 = *(const u16x8*)(src + 8);
    *(u16x8*)&tsm[nl][cc] = v0;
    *(u16x8*)&tsm[nl][cc + 8] = v1;
    __syncthreads();
    int clc = t >> 2, nn = (t & 3) * 16;
    u16x8 o0, o1;
    #pragma unroll
    for (int j = 0; j < 8; ++j) { o0[j] = tsm[nn + j][clc]; o1[j] = tsm[nn + 8 + j][clc]; }
    unsigned short* dst = vT + (size_t)(b * 256 + cb + clc) * 4096 + nb + nn;
    *(u16x8*)dst = o0;
    *(u16x8*)(dst + 8) = o1;
}

// ---------------------------------------------------------------------------
// K5: flash attention, double-buffered pipeline.
// 512 threads = 8 waves, QBLK=128 (16 q-rows/wave), KVBLK=64, kv-split x2.
// Grid = 256 (1 block/CU); XCD decode bid&7 -> (b,half) keeps K/V L2-resident.
// LDS (144KB): K0@0, V0@32K, K1@64K, V1@96K (32KB each), P@128K (8 x 2KB,
// per-wave, dedicated -> no P barrier). One barrier per KV tile (was 3):
//   STAGE(next buf) ; QK(cur) ; softmax ; P ; PV(cur) ; barrier
// Row-sum via MFMA ones-column: accSum rescales with O, so accSum == l_run.
// Q pre-scaled by (1/16)*log2(e); T13 defer-max (THR=8, log2 domain).
// ---------------------------------------------------------------------------
struct AttnState {
    f32x4 acc[16];
    f32x4 accSum;
    float m_run[4];
};

DEV void attn_compute(const char* Ksm, const char* Vsm, char* Psm,
                      const bf16x8 qf[8], AttnState& st, int l) {
    // S = Q·K^T (log2 domain)
    f32x4 s[4];
    __builtin_amdgcn_s_setprio(1);
    #pragma unroll
    for (int jt = 0; jt < 4; ++jt) {
        f32x4 a = f32x4{0.f, 0.f, 0.f, 0.f};
        int jr = jt * 16 + (l & 15);
        #pragma unroll
        for (int ks = 0; ks < 8; ++ks) {
            bf16x8 kb = *(const bf16x8*)(Ksm + jr * 512 + (((ks * 4 + (l >> 4)) ^ (jr & 7)) << 4));
            a = mfma16(qf[ks], kb, a);
        }
        s[jt] = a;
    }
    __builtin_amdgcn_s_setprio(0);

    // tile max (16-lane reduce per row)
    float tm[4];
    #pragma unroll
    for (int r = 0; r < 4; ++r) {
        float v = fmaxf(fmaxf(s[0][r], s[1][r]), fmaxf(s[2][r], s[3][r]));
        #pragma unroll
        for (int mm = 1; mm < 16; mm <<= 1) v = fmaxf(v, __shfl_xor(v, mm));
        tm[r] = v;
    }
    int defer = 1;
    #pragma unroll
    for (int r = 0; r < 4; ++r) defer &= (tm[r] <= st.m_run[r] + 8.f) ? 1 : 0;
    bool alldef = __all(defer);
    if (!alldef) {
        float sf[4];
        #pragma unroll
        for (int r = 0; r < 4; ++r) {
            float mn = fmaxf(st.m_run[r], tm[r]);
            sf[r] = __builtin_amdgcn_exp2f(st.m_run[r] - mn);
            st.m_run[r] = mn;
        }
        #pragma unroll
        for (int i = 0; i < 16; ++i) {
            st.acc[i][0] *= sf[0]; st.acc[i][1] *= sf[1];
            st.acc[i][2] *= sf[2]; st.acc[i][3] *= sf[3];
        }
        st.accSum[0] *= sf[0]; st.accSum[1] *= sf[1];
        st.accSum[2] *= sf[2]; st.accSum[3] *= sf[3];
    }

    // P = exp2(S - m), write bf16 to per-wave LDS (dedicated region)
    #pragma unroll
    for (int jt = 0; jt < 4; ++jt) {
        #pragma unroll
        for (int r = 0; r < 4; ++r) {
            float pv = __builtin_amdgcn_exp2f(s[jt][r] - st.m_run[r]);
            int row = (l >> 4) * 4 + r;
            int j = jt * 16 + (l & 15);
            int byteoff = row * 128 + (((j >> 3) ^ (row & 7)) << 4) + (j & 7) * 2;
            *(unsigned short*)(Psm + byteoff) = f2bf(pv);
        }
    }
    asm volatile("s_waitcnt lgkmcnt(0)" ::: "memory");
    __builtin_amdgcn_sched_barrier(0);

    // O += P · V ; row-sum via ones-column MFMA (accSum tracks l_run exactly)
    bf16x8 onesv;
    #pragma unroll
    for (int j = 0; j < 8; ++j) onesv[j] = (__bf16)1.0f;
    __builtin_amdgcn_s_setprio(1);
    #pragma unroll
    for (int js = 0; js < 2; ++js) {
        int pr = l & 15;
        bf16x8 pa = *(const bf16x8*)(Psm + pr * 128 + (((js * 4 + (l >> 4)) ^ (pr & 7)) << 4));
        #pragma unroll
        for (int sub = 0; sub < 16; ++sub) {
            int cr = sub * 16 + (l & 15);
            bf16x8 vb = *(const bf16x8*)(Vsm + cr * 128 + (((js * 4 + (l >> 4)) ^ (cr & 7)) << 4));
            st.acc[sub] = mfma16(pa, vb, st.acc[sub]);
        }
        st.accSum = mfma16(pa, onesv, st.accSum);
    }
    __builtin_amdgcn_s_setprio(0);
}

#define ATTN_STAGE(KN, VN, kvn)                                                   \
    do {                                                                          \
        _Pragma("unroll")                                                         \
        for (int i_ = 0; i_ < 4; ++i_) {                                          \
            int e_ = (w * 4 + i_) * 64 + l;                                       \
            int r_ = e_ >> 5, p_ = e_ & 31;                                       \
            gload16(kg0 + (size_t)((kvn) + r_) * 768 + ((p_ ^ (r_ & 7)) * 8),     \
                    (KN) + (w * 4 + i_) * 1024);                                  \
        }                                                                         \
        _Pragma("unroll")                                                         \
        for (int i_ = 0; i_ < 4; ++i_) {                                          \
            int e_ = (w * 4 + i_) * 64 + l;                                       \
            int r_ = e_ >> 3, p_ = e_ & 7;                                        \
            gload16(vg0 + (size_t)r_ * 4096 + (kvn) + ((p_ ^ (r_ & 7)) * 8),      \
                    (VN) + (w * 4 + i_) * 1024);                                  \
        }                                                                         \
    } while (0)

__global__ __launch_bounds__(512, 2) void k_attn(const unsigned short* __restrict__ qkvT,
        const unsigned short* __restrict__ vT, unsigned short* __restrict__ Opart,
        float* __restrict__ ml) {
    __shared__ __align__(16) char smem[147456];
    char* Ksm0 = smem;
    char* Vsm0 = smem + 32768;
    char* Ksm1 = smem + 65536;
    char* Vsm1 = smem + 98304;
    int t = threadIdx.x, l = t & 63, w = t >> 6;   // w in 0..7
    char* Psm = smem + 131072 + w * 2048;          // per-wave, dedicated
    int bid = blockIdx.x;
    int combo = bid & 7;
    int b = combo >> 1;
    int half = combo & 1;
    int qb = (bid >> 3) * 128;
    int kv0 = half * 2048;

    const unsigned short* qrow =
        qkvT + (size_t)(b * 4096 + qb + w * 16 + (l & 15)) * 768 + (l >> 4) * 8;
    bf16x8 qf[8];
    #pragma unroll
    for (int ks = 0; ks < 8; ++ks) qf[ks] = *(const bf16x8*)(qrow + ks * 32);

    AttnState st;
    #pragma unroll
    for (int i = 0; i < 16; ++i) st.acc[i] = f32x4{0.f, 0.f, 0.f, 0.f};
    st.accSum = f32x4{0.f, 0.f, 0.f, 0.f};
    #pragma unroll
    for (int r = 0; r < 4; ++r) st.m_run[r] = -3.0e38f;

    const unsigned short* kg0 = qkvT + (size_t)(b * 4096) * 768 + 256;
    const unsigned short* vg0 = vT + (size_t)(b * 256) * 4096;

    ATTN_STAGE(Ksm0, Vsm0, kv0);
    __syncthreads();

    for (int kv = kv0; kv < kv0 + 2048; kv += 128) {
        ATTN_STAGE(Ksm1, Vsm1, kv + 64);
        attn_compute(Ksm0, Vsm0, Psm, qf, st, l);
        __syncthreads();   // drains vmcnt: buf1 staged; buf0 reads done block-wide
        int kvn2 = (kv + 128 < kv0 + 2048) ? (kv + 128) : kv0;  // last: harmless re-stage
        ATTN_STAGE(Ksm0, Vsm0, kvn2);
        attn_compute(Ksm1, Vsm1, Psm, qf, st, l);
        __syncthreads();
    }

    float inv[4];
    #pragma unroll
    for (int r = 0; r < 4; ++r) inv[r] = 1.f / st.accSum[r];
    unsigned short* orow = Opart + (size_t)half * 16384 * 256 +
                           (size_t)(b * 4096 + qb + w * 16) * 256;
    #pragma unroll
    for (int sub = 0; sub < 16; ++sub) {
        #pragma unroll
        for (int r = 0; r < 4; ++r)
            orow[(size_t)((l >> 4) * 4 + r) * 256 + sub * 16 + (l & 15)] = f2bf(st.acc[sub][r] * inv[r]);
    }
    if ((l & 15) == 0) {
        size_t mlbase = (size_t)(b * 4096 + qb + w * 16 + (l >> 4) * 4) * 4;
        #pragma unroll
        for (int r = 0; r < 4; ++r) {
            ml[mlbase + (size_t)r * 4 + half * 2]     = st.m_run[r];
            ml[mlbase + (size_t)r * 4 + half * 2 + 1] = st.accSum[r];
        }
    }
}

// ---------------------------------------------------------------------------
// K5b: combine the two kv-halves: O = w1*O1 + w2*O2, wi = 2^(mi-m) * li / Z.
// ---------------------------------------------------------------------------
__global__ __launch_bounds__(256) void k_combine(const unsigned short* __restrict__ Opart,
        const float* __restrict__ ml, unsigned short* __restrict__ Ot) {
    int gid = blockIdx.x * 256 + threadIdx.x;   // 524288 threads: row = gid>>5, 8 cols each
    int row = gid >> 5;
    int c0 = (gid & 31) * 8;
    float m1 = ml[row * 4], l1 = ml[row * 4 + 1];
    float m2 = ml[row * 4 + 2], l2 = ml[row * 4 + 3];
    float m = fmaxf(m1, m2);
    float a1 = __builtin_amdgcn_exp2f(m1 - m) * l1;
    float a2 = __builtin_amdgcn_exp2f(m2 - m) * l2;
    float inv = 1.f / (a1 + a2);
    float w1 = a1 * inv, w2 = a2 * inv;
    size_t off = (size_t)row * 256 + c0;
    u16x8 o1 = *(const u16x8*)(Opart + off);
    u16x8 o2 = *(const u16x8*)(Opart + (size_t)16384 * 256 + off);
    u16x8 o;
    #pragma unroll
    for (int j = 0; j < 8; ++j) o[j] = f2bf(w1 * bf2f(o1[j]) + w2 * bf2f(o2[j]));
    *(u16x8*)(Ot + off) = o;
}

// ---------------------------------------------------------------------------
// K6: proj GEMM + bias + residual. out(b,c,n) = w_proj @ attn_out + b_proj + xn.
// ---------------------------------------------------------------------------
__global__ __launch_bounds__(256) void k_proj(const unsigned short* __restrict__ Ot,
        const unsigned short* __restrict__ wp, const float* __restrict__ bproj,
        const float* __restrict__ xn, float* __restrict__ out) {
    __shared__ __align__(16) char smem[65536];
    char* Asm = smem;
    char* Bsm = smem + 32768;
    int t = threadIdx.x, l = t & 63, w = t >> 6;
    int mb = blockIdx.x * 64, nb = blockIdx.y * 64;
    #pragma unroll
    for (int i = 0; i < 8; ++i) {
        int idx = (w * 8 + i) * 64 + l;
        int r = idx >> 5, p = idx & 31;
        gload16(Ot + (size_t)(mb + r) * 256 + ((p ^ (r & 7)) * 8), Asm + (w * 8 + i) * 1024);
    }
    #pragma unroll
    for (int i = 0; i < 8; ++i) {
        int idx = (w * 8 + i) * 64 + l;
        int r = idx >> 5, p = idx & 31;
        gload16(wp + (size_t)(nb + r) * 256 + ((p ^ (r & 7)) * 8), Bsm + (w * 8 + i) * 1024);
    }
    __syncthreads();
    int arow = w * 16 + (l & 15);
    bf16x8 af[8];
    #pragma unroll
    for (int ks = 0; ks < 8; ++ks)
        af[ks] = *(const bf16x8*)(Asm + arow * 512 + (((ks * 4 + (l >> 4)) ^ (arow & 7)) << 4));
    f32x4 acc[4];
    #pragma unroll
    for (int i = 0; i < 4; ++i) acc[i] = f32x4{0.f, 0.f, 0.f, 0.f};
    #pragma unroll
    for (int sub = 0; sub < 4; ++sub) {
        int brow = sub * 16 + (l & 15);
        #pragma unroll
        for (int ks = 0; ks < 8; ++ks) {
            bf16x8 bb = *(const bf16x8*)(Bsm + brow * 512 + (((ks * 4 + (l >> 4)) ^ (brow & 7)) << 4));
            acc[sub] = mfma16(af[ks], bb, acc[sub]);
        }
    }
    __syncthreads();  // all waves done reading A/B tiles; reuse LDS for transpose
    float* tr = (float*)smem;  // [64][68] f32
    #pragma unroll
    for (int sub = 0; sub < 4; ++sub) {
        int o = sub * 16 + (l & 15);
        *(f32x4*)(tr + o * 68 + w * 16 + (l >> 4) * 4) = acc[sub];
    }
    __syncthreads();
    int b = mb >> 12;
    int nloc = mb & 4095;
    #pragma unroll
    for (int it = 0; it < 4; ++it) {
        int e = it * 256 + t;
        int o = e >> 4, m4 = (e & 15) * 4;
        f32x4 v = *(const f32x4*)(tr + o * 68 + m4);
        float bv = bproj[nb + o];
        size_t off = ((size_t)(b * 256 + nb + o)) * 4096 + nloc + m4;
        float4 xx = *(const float4*)(xn + off);
        float4 ov;
        ov.x = v[0] + bv + xx.x;
        ov.y = v[1] + bv + xx.y;
        ov.z = v[2] + bv + xx.z;
        ov.w = v[3] + bv + xx.w;
        *(float4*)(out + off) = ov;
    }
}

// ---------------------------------------------------------------------------
extern "C" void kernel_launch(void* const* d_in, const int* in_sizes, int n_in,
                              void* d_out, int out_size, void* d_ws, size_t ws_size,
                              hipStream_t stream) {
    const float* x      = (const float*)d_in[0];
    const float* nscale = (const float*)d_in[1];
    const float* nbias  = (const float*)d_in[2];
    const float* wqkv   = (const float*)d_in[3];
    const float* wproj  = (const float*)d_in[4];
    const float* bproj  = (const float*)d_in[5];
    float* out = (float*)d_out;

    char* ws = (char*)d_ws;
    float* stats = (float*)ws;                                        // 1 KB
    float* xn    = (float*)(ws + 4096);                               // 16 MB fp32 (b,c,n)
    unsigned short* xnT = (unsigned short*)(ws + 4096 + 16777216);    // 8 MB bf16 (b,n,c)
    unsigned short* wq  = (unsigned short*)(ws + 4096 + 16777216 + 8388608);  // 384 KB
    unsigned short* wp  = wq + 768 * 256;                             // 128 KB
    unsigned short* qkvT = wp + 256 * 256;                            // 24 MB bf16 (b,n,768)
    unsigned short* vT   = qkvT + (size_t)16384 * 768;                // 8 MB bf16 (b,c,n)
    unsigned short* Opart = vT + (size_t)4 * 256 * 4096;              // 16 MB bf16 (2,16384,256)
    float* ml = (float*)(Opart + (size_t)2 * 16384 * 256);            // 256 KB
    unsigned short* Ot   = xnT;  // alias: xnT dead after k_qkv

    hipLaunchKernelGGL(k_wconv,   dim3(1024),       dim3(256), 0, stream, wqkv, wproj, wq, wp);
    hipLaunchKernelGGL(k_gnstats, dim3(128),        dim3(256), 0, stream, x, stats);
    hipLaunchKernelGGL(k_gnapply, dim3(64, 4, 4),   dim3(256), 0, stream, x, nscale, nbias, stats, xn, xnT);
    hipLaunchKernelGGL(k_qkv,     dim3(256, 12),    dim3(256), 0, stream, xnT, wq, qkvT);
    hipLaunchKernelGGL(k_vtrans,  dim3(64, 4, 4),   dim3(256), 0, stream, qkvT, vT);
    hipLaunchKernelGGL(k_attn,    dim3(256),        dim3(512), 0, stream, qkvT, vT, Opart, ml);
    hipLaunchKernelGGL(k_combine, dim3(2048),       dim3(256), 0, stream, Opart, ml, Ot);
    hipLaunchKernelGGL(k_proj,    dim3(256, 4),     dim3(256), 0, stream, Ot, wp, bproj, xn, out);
}